// Round 1
// baseline (181.453 us; speedup 1.0000x reference)
//
#include <hip/hip_runtime.h>
#include <stdint.h>

// Problem constants
#define BATCH   4
#define SEQ     2048
#define DMODEL  384
#define NHEAD   6
#define NKVH    2
#define HD      64
#define MTOK    (BATCH*SEQ)   // 8192
#define NQKV    640           // 384 q + 128 k + 128 v
#define QSCALE  0.125f        // 1/sqrt(HD), folded into Q at rope time

typedef __bf16 bf16x8 __attribute__((ext_vector_type(8)));
typedef float  f32x16 __attribute__((ext_vector_type(16)));

__device__ inline unsigned short f2bf(float f) {
  union { float f; unsigned int u; } v; v.f = f;
  return (unsigned short)((v.u + 0x7fffu + ((v.u >> 16) & 1u)) >> 16); // RNE
}
__device__ inline float bf2f(unsigned short b) {
  union { unsigned int u; float f; } v; v.u = ((unsigned int)b) << 16;
  return v.f;
}
__device__ inline unsigned int pack2bf(float a, float b) {
  return (unsigned int)f2bf(a) | ((unsigned int)f2bf(b) << 16);
}

#define GLOAD16(gsrc, ldst) __builtin_amdgcn_global_load_lds( \
    (const __attribute__((address_space(1))) void*)(gsrc), \
    (__attribute__((address_space(3))) void*)(ldst), 16, 0, 0)

// ---------------------------------------------------------------------------
// Kernel 1: prep — X fp32->bf16 ; WT[640][384] = [Wq|Wk|Wv]^T bf16 ; WoT bf16
// ---------------------------------------------------------------------------
__global__ void prep_kernel(const float* __restrict__ X,
                            const float* __restrict__ Wq, const float* __restrict__ Wk,
                            const float* __restrict__ Wv, const float* __restrict__ Wo,
                            unsigned short* __restrict__ Xb,
                            unsigned short* __restrict__ WT,
                            unsigned short* __restrict__ WoT) {
  int idx = blockIdx.x * 256 + threadIdx.x;
  if (idx < (MTOK*DMODEL)/4) {                 // 786432 threads, 4 elems each
    float4 v = ((const float4*)X)[idx];
    union { unsigned short s[4]; uint2 u; } o;
    o.s[0] = f2bf(v.x); o.s[1] = f2bf(v.y); o.s[2] = f2bf(v.z); o.s[3] = f2bf(v.w);
    ((uint2*)Xb)[idx] = o.u;
  } else if (idx < (MTOK*DMODEL)/4 + NQKV*DMODEL) {
    int j = idx - (MTOK*DMODEL)/4;
    int n = j / DMODEL, k = j % DMODEL;
    float val = (n < 384) ? Wq[k*384 + n]
              : (n < 512) ? Wk[k*128 + (n-384)]
                          : Wv[k*128 + (n-512)];
    WT[j] = f2bf(val);
  } else if (idx < (MTOK*DMODEL)/4 + NQKV*DMODEL + DMODEL*DMODEL) {
    int j = idx - (MTOK*DMODEL)/4 - NQKV*DMODEL;
    int n = j / DMODEL, k = j % DMODEL;
    WoT[j] = f2bf(Wo[k*384 + n]);
  }
}

// ---------------------------------------------------------------------------
// Kernel 2/6: bf16 MFMA GEMM  C[M][NCOLS] = A[M][384] * BT[NCOLS][384]^T
// tile 128x64, BK=64, 4 waves (2x2), 32x32x16 MFMA.
// LDS staged via global_load_lds(16B) with XOR-swizzled source slots (T2).
// ---------------------------------------------------------------------------
template<int NCOLS, bool OUT_BF16>
__global__ __launch_bounds__(256, 2)
void gemm_kernel(const unsigned short* __restrict__ A,
                 const unsigned short* __restrict__ BT,
                 void* __restrict__ Cout) {
  __shared__ unsigned short ldsA[128*64];   // [row][64] bf16, 128B rows, swizzled
  __shared__ unsigned short ldsB[64*64];
  const int tid = threadIdx.x;
  const int wid = tid >> 6, lane = tid & 63;
  const int g = lane >> 5, l31 = lane & 31;
  const int wm = wid >> 1, wn = wid & 1;
  const int mbase = blockIdx.x * 128, nbase = blockIdx.y * 64;

  f32x16 c[2];
  #pragma unroll
  for (int i = 0; i < 2; ++i)
    #pragma unroll
    for (int r = 0; r < 16; ++r) c[i][r] = 0.f;

  for (int kt = 0; kt < DMODEL; kt += 64) {
    // stage A (16KB): 4 chunks of 1KB per wave; B (8KB): 2 chunks per wave
    #pragma unroll
    for (int i = 0; i < 4; ++i) {
      int L = ((wid*4 + i) << 10) + lane*16;       // byte offset in ldsA
      int row = L >> 7;
      int slot = (lane & 7) ^ (row & 7);
      GLOAD16(A + (mbase + row)*DMODEL + kt + slot*8, ((char*)ldsA) + L);
    }
    #pragma unroll
    for (int i = 0; i < 2; ++i) {
      int L = ((wid*2 + i) << 10) + lane*16;
      int row = L >> 7;
      int slot = (lane & 7) ^ (row & 7);
      GLOAD16(BT + (nbase + row)*DMODEL + kt + slot*8, ((char*)ldsB) + L);
    }
    __syncthreads();

    bf16x8 bf[4];
    {
      int row = wn*32 + l31;
      #pragma unroll
      for (int s = 0; s < 4; ++s) {
        int slot = ((s<<1) | g) ^ (row & 7);
        bf[s] = *(const bf16x8*)(((const char*)ldsB) + row*128 + slot*16);
      }
    }
    #pragma unroll
    for (int mt = 0; mt < 2; ++mt) {
      int row = wm*64 + mt*32 + l31;
      #pragma unroll
      for (int s = 0; s < 4; ++s) {
        int slot = ((s<<1) | g) ^ (row & 7);
        bf16x8 af = *(const bf16x8*)(((const char*)ldsA) + row*128 + slot*16);
        c[mt] = __builtin_amdgcn_mfma_f32_32x32x16_bf16(af, bf[s], c[mt], 0, 0, 0);
      }
    }
    __syncthreads();
  }

  // epilogue: C layout col=lane&31, row=(r&3)+8*(r>>2)+4*g
  #pragma unroll
  for (int mt = 0; mt < 2; ++mt)
    #pragma unroll
    for (int rr = 0; rr < 16; ++rr) {
      int m = mbase + wm*64 + mt*32 + (rr&3) + ((rr>>2)<<3) + (g<<2);
      int n = nbase + wn*32 + l31;
      float val = c[mt][rr];
      if (OUT_BF16) ((unsigned short*)Cout)[m*NCOLS + n] = f2bf(val);
      else          ((float*)Cout)[m*NCOLS + n] = val;
    }
}

// ---------------------------------------------------------------------------
// Kernel 3: RoPE in-place on Q (scaled by 1/8) and K parts of QKV
// ---------------------------------------------------------------------------
__global__ void rope_kernel(unsigned short* __restrict__ qkv,
                            const float* __restrict__ fcos,
                            const float* __restrict__ fsin) {
  int t = blockIdx.x;          // token 0..8191
  int c = threadIdx.x;         // 0..255 rope pairs (192 q + 64 k)
  int s = t & (SEQ-1);
  int i = c & 31, col;
  float scale;
  if (c < 192) { int h = c >> 5;          col = h*64 + 2*i;        scale = QSCALE; }
  else         { int kvh = (c - 192) >> 5; col = 384 + kvh*64 + 2*i; scale = 1.0f; }
  unsigned int w = *(unsigned int*)(qkv + t*NQKV + col);
  float x0 = bf2f((unsigned short)(w & 0xffff));
  float x1 = bf2f((unsigned short)(w >> 16));
  float cs = fcos[s*32 + i], sn = fsin[s*32 + i];
  float o0 = (x0*cs - x1*sn) * scale;
  float o1 = (x0*sn + x1*cs) * scale;
  *(unsigned int*)(qkv + t*NQKV + col) = pack2bf(o0, o1);
}

// ---------------------------------------------------------------------------
// Kernel 4: V transpose  ->  VT[(b*2+kvh)*64 + hd][2048]
// ---------------------------------------------------------------------------
__global__ void vtrans_kernel(const unsigned short* __restrict__ qkv,
                              unsigned short* __restrict__ VT) {
  int idx = blockIdx.x * 256 + threadIdx.x;  // 131072 total
  int sc  = idx & 255;
  int hd  = (idx >> 8) & 63;
  int kvh = (idx >> 14) & 1;
  int b   = idx >> 15;
  union { unsigned short s[8]; uint4 v; } tmp;
  #pragma unroll
  for (int u = 0; u < 8; ++u)
    tmp.s[u] = qkv[(b*SEQ + sc*8 + u)*NQKV + 512 + kvh*64 + hd];
  *(uint4*)(VT + (((b*2 + kvh)*64 + hd) << 11) + sc*8) = tmp.v;
}

// ---------------------------------------------------------------------------
// Kernel 5: flash attention (non-causal, GQA).
// 2 waves/block, 32 q-rows/wave, KVBLK=64 in LDS (K tile + V^T tile).
// Swapped QK^T: C1[kv][q] = mfma(K, Q) -> lane-local softmax per q (q=lane&31).
// PV: O^T[d][q] = mfma(V^T, P^T). grid = 32 qtiles x 4 b x 6 h = 768 blocks.
// ---------------------------------------------------------------------------
__global__ __launch_bounds__(128, 2)
void attn_kernel(const unsigned short* __restrict__ qkv,
                 const unsigned short* __restrict__ VT,
                 unsigned short* __restrict__ attnO) {
  __shared__ unsigned short ldsK[64*64];   // [kv][hd] swizzled
  __shared__ unsigned short ldsV[64*64];   // [d][kv]  swizzled
  const int tid = threadIdx.x;
  const int wid = tid >> 6, lane = tid & 63;
  const int g = lane >> 5, l31 = lane & 31;
  const int qt = blockIdx.x, b = blockIdx.y, h = blockIdx.z;
  const int kvh = h / 3;
  const int qrow = qt*64 + wid*32 + l31;
  const int token = b*SEQ + qrow;

  // Q fragments (B-operand): lane holds Q[q=lane&31][hd s*16+g*8 .. +7]
  bf16x8 qf[4];
  #pragma unroll
  for (int s = 0; s < 4; ++s)
    qf[s] = *(const bf16x8*)(qkv + token*NQKV + h*64 + s*16 + g*8);

  f32x16 acc0, acc1;                // O^T accum, d-tiles 0/1
  #pragma unroll
  for (int r = 0; r < 16; ++r) { acc0[r] = 0.f; acc1[r] = 0.f; }
  float m = -1e30f, l = 0.f;

  const unsigned short* Kbase = qkv + (b*SEQ)*NQKV + 384 + kvh*64;
  const unsigned short* Vbase = VT + ((b*2 + kvh)*64 << 11);

  for (int kv0 = 0; kv0 < SEQ; kv0 += 64) {
    // stage K tile (wave 0) and V^T tile (wave 1): 8 x 1KB each
    if (wid == 0) {
      #pragma unroll
      for (int i = 0; i < 8; ++i) {
        int L = (i << 10) + lane*16;
        int row = L >> 7;
        int slot = (lane & 7) ^ (row & 7);
        GLOAD16(Kbase + (kv0 + row)*NQKV + slot*8, ((char*)ldsK) + L);
      }
    } else {
      #pragma unroll
      for (int i = 0; i < 8; ++i) {
        int L = (i << 10) + lane*16;
        int row = L >> 7;
        int slot = (lane & 7) ^ (row & 7);
        GLOAD16(Vbase + (row << 11) + kv0 + slot*8, ((char*)ldsV) + L);
      }
    }
    __syncthreads();

    // QK^T: c1[kvt][r] holds score^T for kv = kvt*32 + (r&3)+8*(r>>2)+4g, q = l31
    f32x16 c1[2];
    #pragma unroll
    for (int kvt = 0; kvt < 2; ++kvt) {
      f32x16 cc;
      #pragma unroll
      for (int r = 0; r < 16; ++r) cc[r] = 0.f;
      int row = kvt*32 + l31;
      #pragma unroll
      for (int s = 0; s < 4; ++s) {
        int slot = ((s<<1) | g) ^ (row & 7);
        bf16x8 kf = *(const bf16x8*)(((const char*)ldsK) + row*128 + slot*16);
        cc = __builtin_amdgcn_mfma_f32_32x32x16_bf16(kf, qf[s], cc, 0, 0, 0);
      }
      c1[kvt] = cc;
    }

    // online softmax per q (lane-local + one shfl across g halves)
    float pmax = -1e30f;
    #pragma unroll
    for (int kvt = 0; kvt < 2; ++kvt)
      #pragma unroll
      for (int r = 0; r < 16; ++r) pmax = fmaxf(pmax, c1[kvt][r]);
    pmax = fmaxf(pmax, __shfl_xor(pmax, 32));
    float mnew = fmaxf(m, pmax);
    float alpha = __expf(m - mnew);
    float psum = 0.f;
    #pragma unroll
    for (int kvt = 0; kvt < 2; ++kvt)
      #pragma unroll
      for (int r = 0; r < 16; ++r) {
        float p = __expf(c1[kvt][r] - mnew);
        c1[kvt][r] = p;
        psum += p;
      }
    psum += __shfl_xor(psum, 32);
    l = l*alpha + psum;
    m = mnew;
    #pragma unroll
    for (int r = 0; r < 16; ++r) { acc0[r] *= alpha; acc1[r] *= alpha; }

    // PV: per 16-kv slice build P^T B-frag (pack + cross-half shfl), 2 MFMAs
    #pragma unroll
    for (int kvt = 0; kvt < 2; ++kvt) {
      #pragma unroll
      for (int sl = 0; sl < 2; ++sl) {
        int rbase = sl*8;
        unsigned int w0  = pack2bf(c1[kvt][rbase+0], c1[kvt][rbase+1]);
        unsigned int w1  = pack2bf(c1[kvt][rbase+2], c1[kvt][rbase+3]);
        unsigned int wh0 = pack2bf(c1[kvt][rbase+4], c1[kvt][rbase+5]);
        unsigned int wh1 = pack2bf(c1[kvt][rbase+6], c1[kvt][rbase+7]);
        unsigned int sx0  = __shfl_xor(w0, 32);
        unsigned int sx1  = __shfl_xor(w1, 32);
        unsigned int sxh0 = __shfl_xor(wh0, 32);
        unsigned int sxh1 = __shfl_xor(wh1, 32);
        union { bf16x8 v; unsigned int u[4]; } pf;
        pf.u[0] = g ? sxh0 : w0;
        pf.u[1] = g ? sxh1 : w1;
        pf.u[2] = g ? wh0  : sx0;
        pf.u[3] = g ? wh1  : sx1;
        int kvslice = kvt*32 + sl*16;
        #pragma unroll
        for (int dt = 0; dt < 2; ++dt) {
          int row = dt*32 + l31;
          int slot = ((kvslice >> 3) + g) ^ (row & 7);
          bf16x8 vf = *(const bf16x8*)(((const char*)ldsV) + row*128 + slot*16);
          if (dt == 0) acc0 = __builtin_amdgcn_mfma_f32_32x32x16_bf16(vf, pf.v, acc0, 0, 0, 0);
          else         acc1 = __builtin_amdgcn_mfma_f32_32x32x16_bf16(vf, pf.v, acc1, 0, 0, 0);
        }
      }
    }
    __syncthreads();
  }

  // epilogue: lane holds O^T[d][q=l31]; write 4-bf16 quads
  float invl = 1.0f / l;
  #pragma unroll
  for (int dt = 0; dt < 2; ++dt)
    #pragma unroll
    for (int q8 = 0; q8 < 4; ++q8) {
      union { unsigned short s[4]; uint2 u; } ov;
      #pragma unroll
      for (int j = 0; j < 4; ++j) {
        float v = (dt ? acc1[q8*4+j] : acc0[q8*4+j]) * invl;
        ov.s[j] = f2bf(v);
      }
      int d = dt*32 + q8*8 + g*4;
      *(uint2*)(attnO + token*DMODEL + h*64 + d) = ov.u;
    }
}

// ---------------------------------------------------------------------------
extern "C" void kernel_launch(void* const* d_in, const int* in_sizes, int n_in,
                              void* d_out, int out_size, void* d_ws, size_t ws_size,
                              hipStream_t stream) {
  const float* X    = (const float*)d_in[0];
  const float* Wq   = (const float*)d_in[1];
  const float* Wk   = (const float*)d_in[2];
  const float* Wv   = (const float*)d_in[3];
  const float* Wo   = (const float*)d_in[4];
  const float* fcos = (const float*)d_in[5];
  const float* fsin = (const float*)d_in[6];
  char* ws = (char*)d_ws;

  unsigned short* Xb    = (unsigned short*)(ws);                    //  6,291,456
  unsigned short* QKV   = (unsigned short*)(ws + 6291456);          // 10,485,760
  unsigned short* VTb   = (unsigned short*)(ws + 16777216);         //  2,097,152
  unsigned short* attnO = (unsigned short*)(ws + 18874368);         //  6,291,456
  unsigned short* WT    = (unsigned short*)(ws + 25165824);         //    491,520
  unsigned short* WoT   = (unsigned short*)(ws + 25657344);         //    294,912
  // total ~25.95 MB

  prep_kernel<<<4608, 256, 0, stream>>>(X, Wq, Wk, Wv, Wo, Xb, WT, WoT);
  gemm_kernel<NQKV, true><<<dim3(64, 10), 256, 0, stream>>>(Xb, WT, QKV);
  rope_kernel<<<MTOK, 256, 0, stream>>>(QKV, fcos, fsin);
  vtrans_kernel<<<512, 256, 0, stream>>>(QKV, VTb);
  attn_kernel<<<dim3(32, BATCH, NHEAD), 128, 0, stream>>>(QKV, VTb, attnO);
  gemm_kernel<DMODEL, false><<<dim3(64, 6), 256, 0, stream>>>(attnO, WoT, (void*)d_out);
}

// Round 3
// 177.368 us; speedup vs baseline: 1.0230x; 1.0230x over previous
//
#include <hip/hip_runtime.h>
#include <stdint.h>

// Problem constants
#define BATCH   4
#define SEQ     2048
#define DMODEL  384
#define NHEAD   6
#define NKVH    2
#define HD      64
#define MTOK    (BATCH*SEQ)   // 8192
#define NQKV    640           // 384 q + 128 k + 128 v
// 1/sqrt(HD) * log2(e): scores come out of QK^T already in log2 domain,
// so softmax uses raw v_exp_f32 (2^x) with no per-score multiply.
#define QSCALE  (0.125f * 1.4426950408889634f)

typedef __bf16 bf16x8 __attribute__((ext_vector_type(8)));
typedef float  f32x16 __attribute__((ext_vector_type(16)));

__device__ inline unsigned short f2bf(float f) {
  union { float f; unsigned int u; } v; v.f = f;
  return (unsigned short)((v.u + 0x7fffu + ((v.u >> 16) & 1u)) >> 16); // RNE
}
__device__ inline float bf2f(unsigned short b) {
  union { unsigned int u; float f; } v; v.u = ((unsigned int)b) << 16;
  return v.f;
}
__device__ inline unsigned int pack2bf(float a, float b) {
  return (unsigned int)f2bf(a) | ((unsigned int)f2bf(b) << 16);
}
__device__ inline unsigned int cvtpk(float lo, float hi) {
  unsigned int r;
  asm("v_cvt_pk_bf16_f32 %0, %1, %2" : "=v"(r) : "v"(lo), "v"(hi));
  return r;
}
__device__ inline float exp2_fast(float x) {   // v_exp_f32: D = 2^S0
  float r;
  asm("v_exp_f32 %0, %1" : "=v"(r) : "v"(x));
  return r;
}

#define GLOAD16(gsrc, ldst) __builtin_amdgcn_global_load_lds( \
    (const __attribute__((address_space(1))) void*)(gsrc), \
    (__attribute__((address_space(3))) void*)(ldst), 16, 0, 0)

#define WAITV8() asm volatile("s_waitcnt vmcnt(8)" ::: "memory")
#define WAITV0() asm volatile("s_waitcnt vmcnt(0)" ::: "memory")

// ---------------------------------------------------------------------------
// Kernel 1: prep — X fp32->bf16 ; WT[640][384] = [Wq|Wk|Wv]^T bf16 ; WoT bf16
// ---------------------------------------------------------------------------
__global__ void prep_kernel(const float* __restrict__ X,
                            const float* __restrict__ Wq, const float* __restrict__ Wk,
                            const float* __restrict__ Wv, const float* __restrict__ Wo,
                            unsigned short* __restrict__ Xb,
                            unsigned short* __restrict__ WT,
                            unsigned short* __restrict__ WoT) {
  int idx = blockIdx.x * 256 + threadIdx.x;
  if (idx < (MTOK*DMODEL)/4) {
    float4 v = ((const float4*)X)[idx];
    union { unsigned short s[4]; uint2 u; } o;
    o.s[0] = f2bf(v.x); o.s[1] = f2bf(v.y); o.s[2] = f2bf(v.z); o.s[3] = f2bf(v.w);
    ((uint2*)Xb)[idx] = o.u;
  } else if (idx < (MTOK*DMODEL)/4 + NQKV*DMODEL) {
    int j = idx - (MTOK*DMODEL)/4;
    int n = j / DMODEL, k = j % DMODEL;
    float val = (n < 384) ? Wq[k*384 + n]
              : (n < 512) ? Wk[k*128 + (n-384)]
                          : Wv[k*128 + (n-512)];
    WT[j] = f2bf(val);
  } else if (idx < (MTOK*DMODEL)/4 + NQKV*DMODEL + DMODEL*DMODEL) {
    int j = idx - (MTOK*DMODEL)/4 - NQKV*DMODEL;
    int n = j / DMODEL, k = j % DMODEL;
    WoT[j] = f2bf(Wo[k*384 + n]);
  }
}

// ---------------------------------------------------------------------------
// Kernel 2/6: bf16 MFMA GEMM  C[M][NCOLS] = A[M][384] * BT[NCOLS][384]^T
// tile 128x64, BK=64, 4 waves (2x2), 32x32x16 MFMA. (unchanged from R1)
// ---------------------------------------------------------------------------
template<int NCOLS, bool OUT_BF16>
__global__ __launch_bounds__(256, 2)
void gemm_kernel(const unsigned short* __restrict__ A,
                 const unsigned short* __restrict__ BT,
                 void* __restrict__ Cout) {
  __shared__ unsigned short ldsA[128*64];
  __shared__ unsigned short ldsB[64*64];
  const int tid = threadIdx.x;
  const int wid = tid >> 6, lane = tid & 63;
  const int g = lane >> 5, l31 = lane & 31;
  const int wm = wid >> 1, wn = wid & 1;
  const int mbase = blockIdx.x * 128, nbase = blockIdx.y * 64;

  f32x16 c[2];
  #pragma unroll
  for (int i = 0; i < 2; ++i)
    #pragma unroll
    for (int r = 0; r < 16; ++r) c[i][r] = 0.f;

  for (int kt = 0; kt < DMODEL; kt += 64) {
    #pragma unroll
    for (int i = 0; i < 4; ++i) {
      int L = ((wid*4 + i) << 10) + lane*16;
      int row = L >> 7;
      int slot = (lane & 7) ^ (row & 7);
      GLOAD16(A + (mbase + row)*DMODEL + kt + slot*8, ((char*)ldsA) + L);
    }
    #pragma unroll
    for (int i = 0; i < 2; ++i) {
      int L = ((wid*2 + i) << 10) + lane*16;
      int row = L >> 7;
      int slot = (lane & 7) ^ (row & 7);
      GLOAD16(BT + (nbase + row)*DMODEL + kt + slot*8, ((char*)ldsB) + L);
    }
    __syncthreads();

    bf16x8 bf[4];
    {
      int row = wn*32 + l31;
      #pragma unroll
      for (int s = 0; s < 4; ++s) {
        int slot = ((s<<1) | g) ^ (row & 7);
        bf[s] = *(const bf16x8*)(((const char*)ldsB) + row*128 + slot*16);
      }
    }
    #pragma unroll
    for (int mt = 0; mt < 2; ++mt) {
      int row = wm*64 + mt*32 + l31;
      #pragma unroll
      for (int s = 0; s < 4; ++s) {
        int slot = ((s<<1) | g) ^ (row & 7);
        bf16x8 af = *(const bf16x8*)(((const char*)ldsA) + row*128 + slot*16);
        c[mt] = __builtin_amdgcn_mfma_f32_32x32x16_bf16(af, bf[s], c[mt], 0, 0, 0);
      }
    }
    __syncthreads();
  }

  #pragma unroll
  for (int mt = 0; mt < 2; ++mt)
    #pragma unroll
    for (int rr = 0; rr < 16; ++rr) {
      int m = mbase + wm*64 + mt*32 + (rr&3) + ((rr>>2)<<3) + (g<<2);
      int n = nbase + wn*32 + l31;
      float val = c[mt][rr];
      if (OUT_BF16) ((unsigned short*)Cout)[m*NCOLS + n] = f2bf(val);
      else          ((float*)Cout)[m*NCOLS + n] = val;
    }
}

// ---------------------------------------------------------------------------
// Kernel 3: RoPE in-place on Q (scaled by 1/8*log2e) and K parts of QKV
// ---------------------------------------------------------------------------
__global__ void rope_kernel(unsigned short* __restrict__ qkv,
                            const float* __restrict__ fcos,
                            const float* __restrict__ fsin) {
  int t = blockIdx.x;
  int c = threadIdx.x;
  int s = t & (SEQ-1);
  int i = c & 31, col;
  float scale;
  if (c < 192) { int h = c >> 5;          col = h*64 + 2*i;        scale = QSCALE; }
  else         { int kvh = (c - 192) >> 5; col = 384 + kvh*64 + 2*i; scale = 1.0f; }
  unsigned int w = *(unsigned int*)(qkv + t*NQKV + col);
  float x0 = bf2f((unsigned short)(w & 0xffff));
  float x1 = bf2f((unsigned short)(w >> 16));
  float cs = fcos[s*32 + i], sn = fsin[s*32 + i];
  float o0 = (x0*cs - x1*sn) * scale;
  float o1 = (x0*sn + x1*cs) * scale;
  *(unsigned int*)(qkv + t*NQKV + col) = pack2bf(o0, o1);
}

// ---------------------------------------------------------------------------
// Kernel 4: V transpose via LDS tile  ->  VT[(b*2+kvh)*64 + hd][2048]
// grid (32, 2, 4), 256 threads; 64x64 u16 tile, +8 pad
// ---------------------------------------------------------------------------
__global__ void vtrans_kernel(const unsigned short* __restrict__ qkv,
                              unsigned short* __restrict__ VT) {
  __shared__ unsigned short tile[64][72];
  int t = threadIdx.x;
  int s0 = blockIdx.x * 64;
  int kvh = blockIdx.y;
  int b = blockIdx.z;
  #pragma unroll
  for (int p = 0; p < 2; ++p) {
    int row = (t >> 3) + p*32;
    int c8 = t & 7;
    uint4 v = *(const uint4*)(qkv + (size_t)(b*SEQ + s0 + row)*NQKV + 512 + kvh*64 + c8*8);
    *(uint4*)(&tile[row][c8*8]) = v;
  }
  __syncthreads();
  #pragma unroll
  for (int p = 0; p < 2; ++p) {
    int d = (t >> 3) + p*32;
    int sj = t & 7;
    union { unsigned short s[8]; uint4 v; } o;
    #pragma unroll
    for (int u = 0; u < 8; ++u) o.s[u] = tile[sj*8 + u][d];
    *(uint4*)(VT + (size_t)((b*2 + kvh)*64 + d)*SEQ + s0 + sj*8) = o.v;
  }
}

// ---------------------------------------------------------------------------
// Kernel 5: flash attention, barrier-free pipelined.
// 1536 blocks (XCD-swizzled), 128 thr = 2 waves; block owns 32 q rows; wave w
// covers kv half w (1024 kv) in 32 tiles of 32, double-buffered per-wave LDS
// (K[32][64] + VT[64][32] per buf = 8KB, x2 bufs x2 waves = 32KB). Counted
// vmcnt(8) keeps next tile's 8 global_load_lds in flight. Flash-combine of
// the two kv halves through LDS at the end.
// V-tile swizzle involution X(row) = (row&3)^((row>>2)&3): 4-way (not 8-way)
// bank aliasing on the PV ds_read_b128.
// ---------------------------------------------------------------------------
__device__ __forceinline__ void stage_tile(const unsigned short* Kbase,
                                           const unsigned short* Vbase,
                                           int kv0, char* kbuf, char* vbuf, int lane) {
  #pragma unroll
  for (int i = 0; i < 4; ++i) {                 // K: [32][128B] rows, 8 slots
    int L = (i << 10) + lane*16;
    int row = L >> 7;
    int slot = (lane & 7) ^ (row & 7);
    GLOAD16(Kbase + (kv0 + row)*NQKV + slot*8, kbuf + L);
  }
  #pragma unroll
  for (int i = 0; i < 4; ++i) {                 // VT: [64][64B] rows, 4 slots
    int L = (i << 10) + lane*16;
    int row = L >> 6;
    int sl4 = (lane & 3) ^ (row & 3) ^ ((row >> 2) & 3);
    GLOAD16(Vbase + row*SEQ + kv0 + sl4*8, vbuf + L);
  }
}

__global__ __launch_bounds__(128, 2)
void attn_kernel(const unsigned short* __restrict__ qkv,
                 const unsigned short* __restrict__ VT,
                 unsigned short* __restrict__ attnO) {
  __shared__ __align__(16) char smem[32768];
  const int tid = threadIdx.x;
  const int wid = tid >> 6, lane = tid & 63;
  const int g = lane >> 5, l31 = lane & 31;

  // bijective XCD swizzle: 1536 blocks = 8 chunks of 192; chunk ~ 3 (b,h) pairs
  int bid = blockIdx.x;
  int e = (bid & 7)*192 + (bid >> 3);
  int qt = e & 63;
  int hb = e >> 6;
  int h = hb % 6, b = hb / 6;
  const int kvh = h / 3;
  const int token = b*SEQ + qt*32 + l31;
  const int kvbase = wid * (SEQ/2);

  char* kb0 = smem + wid*16384;         // [buf]: +0 K(4KB), +4096 V(4KB), buf stride 8192
  char* vb0 = kb0 + 4096;

  bf16x8 qf[4];
  #pragma unroll
  for (int s = 0; s < 4; ++s)
    qf[s] = *(const bf16x8*)(qkv + (size_t)token*NQKV + h*64 + s*16 + g*8);

  f32x16 acc0, acc1;
  #pragma unroll
  for (int r = 0; r < 16; ++r) { acc0[r] = 0.f; acc1[r] = 0.f; }
  float m = -1e30f, l = 0.f;

  const unsigned short* Kbase = qkv + (size_t)(b*SEQ)*NQKV + 384 + kvh*64;
  const unsigned short* Vbase = VT + (size_t)((b*2 + kvh)*64)*SEQ;

  stage_tile(Kbase, Vbase, kvbase, kb0, vb0, lane);

  for (int t = 0; t < 32; ++t) {
    int cur = t & 1;
    if (t < 31)
      stage_tile(Kbase, Vbase, kvbase + (t+1)*32,
                 kb0 + ((t+1)&1)*8192, vb0 + ((t+1)&1)*8192, lane);
    if (t < 31) { WAITV8(); } else { WAITV0(); }

    const char* kb = kb0 + cur*8192;
    const char* vb = vb0 + cur*8192;

    // QK^T: c1[r] = score^T[kv = (r&3)+8*(r>>2)+4g][q = l31]  (log2 domain)
    f32x16 c1;
    #pragma unroll
    for (int r = 0; r < 16; ++r) c1[r] = 0.f;
    {
      int row = l31;
      #pragma unroll
      for (int s = 0; s < 4; ++s) {
        int slot = ((s<<1) | g) ^ (row & 7);
        bf16x8 kf = *(const bf16x8*)(kb + row*128 + slot*16);
        c1 = __builtin_amdgcn_mfma_f32_32x32x16_bf16(kf, qf[s], c1, 0, 0, 0);
      }
    }

    // online softmax (defer-max, log2 units)
    float pmax = c1[0];
    #pragma unroll
    for (int r = 1; r < 16; ++r) pmax = fmaxf(pmax, c1[r]);
    pmax = fmaxf(pmax, __shfl_xor(pmax, 32));
    if (!__all(pmax <= m + 10.f)) {
      float mnew = fmaxf(m, pmax);
      float alpha = exp2_fast(m - mnew);
      #pragma unroll
      for (int r = 0; r < 16; ++r) { acc0[r] *= alpha; acc1[r] *= alpha; }
      l *= alpha;
      m = mnew;
    }
    float p[16]; float psum = 0.f;
    #pragma unroll
    for (int r = 0; r < 16; ++r) {
      p[r] = exp2_fast(c1[r] - m);
      psum += p[r];
    }
    l += psum;   // per-g-half partial; merged once at the end

    // PV: per 16-kv slice build P^T frag (cvt_pk + 2 shfl exchange), 2 MFMAs
    #pragma unroll
    for (int sl = 0; sl < 2; ++sl) {
      int rb = sl*8;
      unsigned int w0  = cvtpk(p[rb+0], p[rb+1]);
      unsigned int w1  = cvtpk(p[rb+2], p[rb+3]);
      unsigned int wh0 = cvtpk(p[rb+4], p[rb+5]);
      unsigned int wh1 = cvtpk(p[rb+6], p[rb+7]);
      unsigned int s0 = g ? w0 : wh0;
      unsigned int s1 = g ? w1 : wh1;
      unsigned int r0 = __shfl_xor(s0, 32);
      unsigned int r1 = __shfl_xor(s1, 32);
      union { bf16x8 v; unsigned int u[4]; } pf;
      pf.u[0] = g ? r0  : w0;
      pf.u[1] = g ? r1  : w1;
      pf.u[2] = g ? wh0 : r0;
      pf.u[3] = g ? wh1 : r1;
      #pragma unroll
      for (int dt = 0; dt < 2; ++dt) {
        int row = dt*32 + l31;
        int t16 = (sl*2 + g) ^ (row & 3) ^ ((row >> 2) & 3);
        bf16x8 vf = *(const bf16x8*)(vb + row*64 + t16*16);
        if (dt == 0) acc0 = __builtin_amdgcn_mfma_f32_32x32x16_bf16(vf, pf.v, acc0, 0, 0, 0);
        else         acc1 = __builtin_amdgcn_mfma_f32_32x32x16_bf16(vf, pf.v, acc1, 0, 0, 0);
      }
    }
  }

  // merge g halves of l, then flash-combine the two waves' kv halves
  l += __shfl_xor(l, 32);
  __syncthreads();                       // staging LDS now dead everywhere
  float* cmb  = (float*)smem;            // [2][2][32] m,l
  float* accx = (float*)(smem + 512);    // [64][32] fp32
  if (g == 0) { cmb[wid*64 + l31] = m; cmb[wid*64 + 32 + l31] = l; }
  __syncthreads();
  int ow = wid ^ 1;
  float m_o = cmb[ow*64 + l31], l_o = cmb[ow*64 + 32 + l31];
  float ms = fmaxf(m, m_o);
  float a = exp2_fast(m - ms);
  if (wid == 1) {
    #pragma unroll
    for (int dt = 0; dt < 2; ++dt)
      #pragma unroll
      for (int r = 0; r < 16; ++r) {
        int d = dt*32 + (r&3) + ((r>>2)<<3) + (g<<2);
        accx[d*32 + l31] = (dt ? acc1[r] : acc0[r]) * a;
      }
  }
  __syncthreads();
  if (wid == 0) {
    float a_o = exp2_fast(m_o - ms);
    float lstar = l*a + l_o*a_o;
    float invl = 1.0f / lstar;
    #pragma unroll
    for (int dt = 0; dt < 2; ++dt)
      #pragma unroll
      for (int q8 = 0; q8 < 4; ++q8) {
        union { unsigned short s[4]; uint2 u; } ov;
        #pragma unroll
        for (int j = 0; j < 4; ++j) {
          int r = q8*4 + j;
          int d = dt*32 + (r&3) + ((r>>2)<<3) + (g<<2);
          float tot = (dt ? acc1[r] : acc0[r])*a + accx[d*32 + l31];
          ov.s[j] = f2bf(tot * invl);
        }
        int d0 = dt*32 + q8*8 + g*4;
        *(uint2*)(attnO + (size_t)token*DMODEL + h*64 + d0) = ov.u;
      }
  }
}

// ---------------------------------------------------------------------------
extern "C" void kernel_launch(void* const* d_in, const int* in_sizes, int n_in,
                              void* d_out, int out_size, void* d_ws, size_t ws_size,
                              hipStream_t stream) {
  const float* X    = (const float*)d_in[0];
  const float* Wq   = (const float*)d_in[1];
  const float* Wk   = (const float*)d_in[2];
  const float* Wv   = (const float*)d_in[3];
  const float* Wo   = (const float*)d_in[4];
  const float* fcos = (const float*)d_in[5];
  const float* fsin = (const float*)d_in[6];
  char* ws = (char*)d_ws;

  unsigned short* Xb    = (unsigned short*)(ws);
  unsigned short* QKV   = (unsigned short*)(ws + 6291456);
  unsigned short* VTb   = (unsigned short*)(ws + 16777216);
  unsigned short* attnO = (unsigned short*)(ws + 18874368);
  unsigned short* WT    = (unsigned short*)(ws + 25165824);
  unsigned short* WoT   = (unsigned short*)(ws + 25657344);

  prep_kernel<<<4608, 256, 0, stream>>>(X, Wq, Wk, Wv, Wo, Xb, WT, WoT);
  gemm_kernel<NQKV, true><<<dim3(64, 10), 256, 0, stream>>>(Xb, WT, QKV);
  rope_kernel<<<MTOK, 256, 0, stream>>>(QKV, fcos, fsin);
  vtrans_kernel<<<dim3(32, 2, 4), 256, 0, stream>>>(QKV, VTb);
  attn_kernel<<<1536, 128, 0, stream>>>(QKV, VTb, attnO);
  gemm_kernel<DMODEL, false><<<dim3(64, 6), 256, 0, stream>>>(attnO, WoT, (void*)d_out);
}

// Round 5
// 155.020 us; speedup vs baseline: 1.1705x; 1.1442x over previous
//
#include <hip/hip_runtime.h>
#include <stdint.h>

// Problem constants
#define BATCH   4
#define SEQ     2048
#define DMODEL  384
#define NHEAD   6
#define NKVH    2
#define HD      64
#define MTOK    (BATCH*SEQ)   // 8192
#define NQKV    640           // 384 q + 128 k + 128 v
// 1/sqrt(HD) * log2(e): scores leave QK^T already in log2 domain -> raw v_exp_f32.
#define QSCALE  (0.125f * 1.4426950408889634f)

typedef __bf16 bf16x8 __attribute__((ext_vector_type(8)));
typedef float  f32x16 __attribute__((ext_vector_type(16)));

__device__ inline unsigned short f2bf(float f) {
  union { float f; unsigned int u; } v; v.f = f;
  return (unsigned short)((v.u + 0x7fffu + ((v.u >> 16) & 1u)) >> 16); // RNE
}
__device__ inline float bf2f(unsigned short b) {
  union { unsigned int u; float f; } v; v.u = ((unsigned int)b) << 16;
  return v.f;
}
__device__ inline unsigned int cvtpk(float lo, float hi) {
  unsigned int r;
  asm("v_cvt_pk_bf16_f32 %0, %1, %2" : "=v"(r) : "v"(lo), "v"(hi));
  return r;
}
__device__ inline float exp2_fast(float x) {   // v_exp_f32: D = 2^S0
  float r;
  asm("v_exp_f32 %0, %1" : "=v"(r) : "v"(x));
  return r;
}

#define GLOAD16(gsrc, ldst) __builtin_amdgcn_global_load_lds( \
    (const __attribute__((address_space(1))) void*)(gsrc), \
    (__attribute__((address_space(3))) void*)(ldst), 16, 0, 0)

// ---------------------------------------------------------------------------
// Kernel 1: prep — X fp32->bf16 ; WT[640][384] = [Wq|Wk|Wv]^T bf16 ; WoT bf16
// ---------------------------------------------------------------------------
__global__ void prep_kernel(const float* __restrict__ X,
                            const float* __restrict__ Wq, const float* __restrict__ Wk,
                            const float* __restrict__ Wv, const float* __restrict__ Wo,
                            unsigned short* __restrict__ Xb,
                            unsigned short* __restrict__ WT,
                            unsigned short* __restrict__ WoT) {
  int idx = blockIdx.x * 256 + threadIdx.x;
  if (idx < (MTOK*DMODEL)/4) {
    float4 v = ((const float4*)X)[idx];
    union { unsigned short s[4]; uint2 u; } o;
    o.s[0] = f2bf(v.x); o.s[1] = f2bf(v.y); o.s[2] = f2bf(v.z); o.s[3] = f2bf(v.w);
    ((uint2*)Xb)[idx] = o.u;
  } else if (idx < (MTOK*DMODEL)/4 + NQKV*DMODEL) {
    int j = idx - (MTOK*DMODEL)/4;
    int n = j / DMODEL, k = j % DMODEL;
    float val = (n < 384) ? Wq[k*384 + n]
              : (n < 512) ? Wk[k*128 + (n-384)]
                          : Wv[k*128 + (n-512)];
    WT[j] = f2bf(val);
  } else if (idx < (MTOK*DMODEL)/4 + NQKV*DMODEL + DMODEL*DMODEL) {
    int j = idx - (MTOK*DMODEL)/4 - NQKV*DMODEL;
    int n = j / DMODEL, k = j % DMODEL;
    WoT[j] = f2bf(Wo[k*384 + n]);
  }
}

// ---------------------------------------------------------------------------
// Kernel 2/5: bf16 MFMA GEMM  C[M][NCOLS] = A[M][384] * BT[NCOLS][384]^T
// tile 128x64, BK=64, 4 waves (2x2), 32x32x16 MFMA.
// ROPE: fuse rotary embedding in epilogue for n-tiles < 8 (Q heads get QSCALE,
// K heads scale 1). Pair exchange via shfl_xor(1); i = (n&63)>>1; s = m&2047.
// ---------------------------------------------------------------------------
template<int NCOLS, bool OUT_BF16, bool ROPE>
__global__ __launch_bounds__(256, 2)
void gemm_kernel(const unsigned short* __restrict__ A,
                 const unsigned short* __restrict__ BT,
                 void* __restrict__ Cout,
                 const float* __restrict__ fcos,
                 const float* __restrict__ fsin) {
  __shared__ unsigned short ldsA[128*64];
  __shared__ unsigned short ldsB[64*64];
  const int tid = threadIdx.x;
  const int wid = tid >> 6, lane = tid & 63;
  const int g = lane >> 5, l31 = lane & 31;
  const int wm = wid >> 1, wn = wid & 1;
  const int mbase = blockIdx.x * 128, nbase = blockIdx.y * 64;

  f32x16 c[2];
  #pragma unroll
  for (int i = 0; i < 2; ++i)
    #pragma unroll
    for (int r = 0; r < 16; ++r) c[i][r] = 0.f;

  for (int kt = 0; kt < DMODEL; kt += 64) {
    #pragma unroll
    for (int i = 0; i < 4; ++i) {
      int L = ((wid*4 + i) << 10) + lane*16;
      int row = L >> 7;
      int slot = (lane & 7) ^ (row & 7);
      GLOAD16(A + (mbase + row)*DMODEL + kt + slot*8, ((char*)ldsA) + L);
    }
    #pragma unroll
    for (int i = 0; i < 2; ++i) {
      int L = ((wid*2 + i) << 10) + lane*16;
      int row = L >> 7;
      int slot = (lane & 7) ^ (row & 7);
      GLOAD16(BT + (nbase + row)*DMODEL + kt + slot*8, ((char*)ldsB) + L);
    }
    __syncthreads();

    bf16x8 bf[4];
    {
      int row = wn*32 + l31;
      #pragma unroll
      for (int s = 0; s < 4; ++s) {
        int slot = ((s<<1) | g) ^ (row & 7);
        bf[s] = *(const bf16x8*)(((const char*)ldsB) + row*128 + slot*16);
      }
    }
    #pragma unroll
    for (int mt = 0; mt < 2; ++mt) {
      int row = wm*64 + mt*32 + l31;
      #pragma unroll
      for (int s = 0; s < 4; ++s) {
        int slot = ((s<<1) | g) ^ (row & 7);
        bf16x8 af = *(const bf16x8*)(((const char*)ldsA) + row*128 + slot*16);
        c[mt] = __builtin_amdgcn_mfma_f32_32x32x16_bf16(af, bf[s], c[mt], 0, 0, 0);
      }
    }
    __syncthreads();
  }

  const int n = nbase + wn*32 + l31;
  const bool isqk = ROPE && (nbase < 512);
  const float rscale = (nbase < 384) ? QSCALE : 1.0f;
  const int ri = (n & 63) >> 1;
  const bool odd = (n & 1) != 0;

  #pragma unroll
  for (int mt = 0; mt < 2; ++mt)
    #pragma unroll
    for (int rr = 0; rr < 16; ++rr) {
      int m = mbase + wm*64 + mt*32 + (rr&3) + ((rr>>2)<<3) + (g<<2);
      float val = c[mt][rr];
      if (isqk) {
        float xp = __shfl_xor(val, 1);
        int s = m & (SEQ-1);
        float cs = fcos[s*32 + ri], sn = fsin[s*32 + ri];
        val = odd ? (xp*sn + val*cs) : (val*cs - xp*sn);
        val *= rscale;
      }
      if (OUT_BF16) ((unsigned short*)Cout)[m*NCOLS + n] = f2bf(val);
      else          ((float*)Cout)[m*NCOLS + n] = val;
    }
}

// ---------------------------------------------------------------------------
// Kernel 3: V -> MFMA-fragment layout
// Vf[(b*2+kvh)][tile(64)][dt(2)][sl(2)][lane(64)][8 bf16]
// content: V[s = tile*32 + sl*16 + (lane>>5)*8 + j][hd = dt*32 + (lane&31)]
// ---------------------------------------------------------------------------
__global__ void vfrag_kernel(const unsigned short* __restrict__ qkv,
                             unsigned short* __restrict__ Vf) {
  __shared__ unsigned short tile[64][72];
  int t = threadIdx.x;
  int s0 = blockIdx.x * 64;
  int kvh = blockIdx.y;
  int b = blockIdx.z;
  #pragma unroll
  for (int p = 0; p < 2; ++p) {
    int row = (t >> 3) + p*32;
    int c8 = t & 7;
    uint4 v = *(const uint4*)(qkv + (size_t)(b*SEQ + s0 + row)*NQKV + 512 + kvh*64 + c8*8);
    *(uint4*)(&tile[row][c8*8]) = v;
  }
  __syncthreads();
  unsigned short* base = Vf + (size_t)(b*2 + kvh)*131072;
  #pragma unroll
  for (int p = 0; p < 2; ++p) {
    int c = t + p*256;           // 0..511
    int tloc = c >> 8;
    int r = c & 255;
    int dt = r >> 7, sl = (r >> 6) & 1, lane = r & 63;
    int gg = lane >> 5, ll = lane & 31;
    union { unsigned short s[8]; uint4 v; } o;
    #pragma unroll
    for (int j = 0; j < 8; ++j)
      o.s[j] = tile[tloc*32 + sl*16 + gg*8 + j][dt*32 + ll];
    *(uint4*)(base + (size_t)(s0/32 + tloc)*2048 + (dt*2 + sl)*512 + lane*8) = o.v;
  }
}

// ---------------------------------------------------------------------------
// Kernel 4: flash attention — 1 wave/block, barrier-free, kv-split 2.
// grid (1536, 2): x = XCD-swizzled (qt, h, b); y = kv part (1024 kv each).
// K double-buffered in LDS (8KB); V fragments direct global->VGPR (coalesced,
// prefetch depth 1, named reg sets). Counted vmcnt(8). Partials (bf16 unnorm
// O + fp32 m,l) to workspace; combine kernel merges.
// ---------------------------------------------------------------------------
__device__ __forceinline__ void stage_k(const unsigned short* Kbase, int kv0,
                                        char* kbuf, int lane) {
  #pragma unroll
  for (int i = 0; i < 4; ++i) {
    int L = (i << 10) + lane*16;
    int row = L >> 7;
    int slot = (lane & 7) ^ (row & 7);
    GLOAD16(Kbase + (size_t)(kv0 + row)*NQKV + slot*8, kbuf + L);
  }
}

#define ATTN_BODY(T, VC0, VC1, VC2, VC3, VN0, VN1, VN2, VN3, PREF) do {            \
  if (PREF) {                                                                      \
    stage_k(Kbase, kvbase + ((T)+1)*32, kbuf + (((T)+1)&1)*4096, lane);            \
    const unsigned short* vp = Vfb + (size_t)(part*32 + (T)+1)*2048;               \
    VN0 = *(const bf16x8*)(vp + lane*8);                                           \
    VN1 = *(const bf16x8*)(vp + 512 + lane*8);                                     \
    VN2 = *(const bf16x8*)(vp + 1024 + lane*8);                                    \
    VN3 = *(const bf16x8*)(vp + 1536 + lane*8);                                    \
    asm volatile("s_waitcnt vmcnt(8)" ::: "memory");                               \
  } else {                                                                         \
    asm volatile("s_waitcnt vmcnt(0)" ::: "memory");                               \
  }                                                                                \
  const char* kb = kbuf + ((T)&1)*4096;                                            \
  f32x16 c1;                                                                       \
  _Pragma("unroll")                                                                \
  for (int r = 0; r < 16; ++r) c1[r] = 0.f;                                        \
  _Pragma("unroll")                                                                \
  for (int s = 0; s < 4; ++s) {                                                    \
    int slot = ((s<<1) | g) ^ (l31 & 7);                                           \
    bf16x8 kf = *(const bf16x8*)(kb + l31*128 + slot*16);                          \
    c1 = __builtin_amdgcn_mfma_f32_32x32x16_bf16(kf, qf[s], c1, 0, 0, 0);          \
  }                                                                                \
  float x0 = fmaxf(c1[0],c1[1]), x1 = fmaxf(c1[2],c1[3]);                          \
  float x2 = fmaxf(c1[4],c1[5]), x3 = fmaxf(c1[6],c1[7]);                          \
  float x4 = fmaxf(c1[8],c1[9]), x5 = fmaxf(c1[10],c1[11]);                        \
  float x6 = fmaxf(c1[12],c1[13]), x7 = fmaxf(c1[14],c1[15]);                      \
  float y0 = fmaxf(x0,x1), y1 = fmaxf(x2,x3), y2 = fmaxf(x4,x5), y3 = fmaxf(x6,x7);\
  float pmax = fmaxf(fmaxf(y0,y1), fmaxf(y2,y3));                                  \
  pmax = fmaxf(pmax, __shfl_xor(pmax, 32));                                        \
  if (!__all(pmax <= mrun + 10.f)) {                                               \
    float mnew = fmaxf(mrun, pmax);                                                \
    float alpha = exp2_fast(mrun - mnew);                                          \
    _Pragma("unroll")                                                              \
    for (int r = 0; r < 16; ++r) { acc0[r] *= alpha; acc1[r] *= alpha; }           \
    lrun *= alpha;                                                                 \
    mrun = mnew;                                                                   \
  }                                                                                \
  float p[16];                                                                     \
  _Pragma("unroll")                                                                \
  for (int r = 0; r < 16; ++r) p[r] = exp2_fast(c1[r] - mrun);                     \
  {                                                                                \
    float s0_ = (p[0]+p[1])+(p[2]+p[3]), s1_ = (p[4]+p[5])+(p[6]+p[7]);            \
    float s2_ = (p[8]+p[9])+(p[10]+p[11]), s3_ = (p[12]+p[13])+(p[14]+p[15]);      \
    lrun += (s0_+s1_)+(s2_+s3_);                                                   \
  }                                                                                \
  _Pragma("unroll")                                                                \
  for (int sl = 0; sl < 2; ++sl) {                                                 \
    int rb = sl*8;                                                                 \
    unsigned int w0  = cvtpk(p[rb+0], p[rb+1]);                                    \
    unsigned int w1  = cvtpk(p[rb+2], p[rb+3]);                                    \
    unsigned int wh0 = cvtpk(p[rb+4], p[rb+5]);                                    \
    unsigned int wh1 = cvtpk(p[rb+6], p[rb+7]);                                    \
    unsigned int t0 = g ? w0 : wh0;                                                \
    unsigned int t1 = g ? w1 : wh1;                                                \
    unsigned int r0 = __shfl_xor(t0, 32);                                          \
    unsigned int r1 = __shfl_xor(t1, 32);                                          \
    union { bf16x8 v; unsigned int u[4]; } pf;                                     \
    pf.u[0] = g ? r0  : w0;                                                        \
    pf.u[1] = g ? r1  : w1;                                                        \
    pf.u[2] = g ? wh0 : r0;                                                        \
    pf.u[3] = g ? wh1 : r1;                                                        \
    if (sl == 0) {                                                                 \
      acc0 = __builtin_amdgcn_mfma_f32_32x32x16_bf16(VC0, pf.v, acc0, 0, 0, 0);    \
      acc1 = __builtin_amdgcn_mfma_f32_32x32x16_bf16(VC2, pf.v, acc1, 0, 0, 0);    \
    } else {                                                                       \
      acc0 = __builtin_amdgcn_mfma_f32_32x32x16_bf16(VC1, pf.v, acc0, 0, 0, 0);    \
      acc1 = __builtin_amdgcn_mfma_f32_32x32x16_bf16(VC3, pf.v, acc1, 0, 0, 0);    \
    }                                                                              \
  }                                                                                \
} while (0)

__global__ __launch_bounds__(64, 3)
void attn_kernel(const unsigned short* __restrict__ qkv,
                 const unsigned short* __restrict__ Vf,
                 unsigned short* __restrict__ PO0,
                 unsigned short* __restrict__ PO1,
                 float2* __restrict__ ML) {
  __shared__ __align__(16) char kbuf[8192];
  const int lane = threadIdx.x;
  const int g = lane >> 5, l31 = lane & 31;

  int bid = blockIdx.x;
  const int part = blockIdx.y;
  int e = (bid & 7)*192 + (bid >> 3);     // bijective XCD swizzle (1536 = 8*192)
  int qt = e & 63;
  int hb = e >> 6;
  int h = hb % 6, b = hb / 6;
  const int kvh = h / 3;
  const int token = b*SEQ + qt*32 + l31;
  const int kvbase = part * (SEQ/2);

  bf16x8 qf[4];
  #pragma unroll
  for (int s = 0; s < 4; ++s)
    qf[s] = *(const bf16x8*)(qkv + (size_t)token*NQKV + h*64 + s*16 + g*8);

  f32x16 acc0, acc1;
  #pragma unroll
  for (int r = 0; r < 16; ++r) { acc0[r] = 0.f; acc1[r] = 0.f; }
  float mrun = -1e30f, lrun = 0.f;

  const unsigned short* Kbase = qkv + (size_t)(b*SEQ)*NQKV + 384 + kvh*64;
  const unsigned short* Vfb = Vf + (size_t)(b*2 + kvh)*131072;

  bf16x8 vA0, vA1, vA2, vA3, vB0, vB1, vB2, vB3;

  // prologue: batch 0 (K tile 0 -> buf0, V frags tile 0 -> set A)
  stage_k(Kbase, kvbase, kbuf, lane);
  {
    const unsigned short* vp = Vfb + (size_t)(part*32)*2048;
    vA0 = *(const bf16x8*)(vp + lane*8);
    vA1 = *(const bf16x8*)(vp + 512 + lane*8);
    vA2 = *(const bf16x8*)(vp + 1024 + lane*8);
    vA3 = *(const bf16x8*)(vp + 1536 + lane*8);
  }

  for (int tt = 0; tt < 30; tt += 2) {
    ATTN_BODY(tt,   vA0, vA1, vA2, vA3, vB0, vB1, vB2, vB3, true);
    ATTN_BODY(tt+1, vB0, vB1, vB2, vB3, vA0, vA1, vA2, vA3, true);
  }
  ATTN_BODY(30, vA0, vA1, vA2, vA3, vB0, vB1, vB2, vB3, true);
  ATTN_BODY(31, vB0, vB1, vB2, vB3, vA0, vA1, vA2, vA3, false);

  // epilogue: merge g-halves of l; write unnormalized O (bf16) + (m,l)
  lrun += __shfl_xor(lrun, 32);
  unsigned short* PO = part ? PO1 : PO0;
  #pragma unroll
  for (int dt = 0; dt < 2; ++dt)
    #pragma unroll
    for (int q8 = 0; q8 < 4; ++q8) {
      union { unsigned short s[4]; uint2 u; } ov;
      #pragma unroll
      for (int j = 0; j < 4; ++j) {
        int r = q8*4 + j;
        ov.s[j] = f2bf(dt ? acc1[r] : acc0[r]);
      }
      int d = dt*32 + q8*8 + g*4;
      *(uint2*)(PO + (size_t)token*DMODEL + h*64 + d) = ov.u;
    }
  if (g == 0)
    ML[(size_t)part*49152 + token*6 + h] = make_float2(mrun, lrun);
}

// ---------------------------------------------------------------------------
// Kernel 5b: combine the two kv-split partials -> attnO bf16
// ---------------------------------------------------------------------------
__global__ void combine_kernel(const unsigned short* __restrict__ PO0,
                               const unsigned short* __restrict__ PO1,
                               const float2* __restrict__ ML,
                               unsigned short* __restrict__ attnO) {
  int idx = blockIdx.x*256 + threadIdx.x;   // 393216 chunks of 8 elems
  int token = idx / 48;
  int c8 = idx - token*48;
  int h = c8 >> 3;
  float2 ml0 = ML[token*6 + h];
  float2 ml1 = ML[49152 + token*6 + h];
  float M = fmaxf(ml0.x, ml1.x);
  float a0 = exp2_fast(ml0.x - M), a1 = exp2_fast(ml1.x - M);
  float inv = 1.0f / (ml0.y*a0 + ml1.y*a1);
  float s0 = a0*inv, s1 = a1*inv;
  union { unsigned short s[8]; uint4 v; } p0, p1, o;
  p0.v = *(const uint4*)(PO0 + (size_t)idx*8);
  p1.v = *(const uint4*)(PO1 + (size_t)idx*8);
  #pragma unroll
  for (int j = 0; j < 8; ++j)
    o.s[j] = f2bf(bf2f(p0.s[j])*s0 + bf2f(p1.s[j])*s1);
  *(uint4*)(attnO + (size_t)idx*8) = o.v;
}

// ---------------------------------------------------------------------------
extern "C" void kernel_launch(void* const* d_in, const int* in_sizes, int n_in,
                              void* d_out, int out_size, void* d_ws, size_t ws_size,
                              hipStream_t stream) {
  const float* X    = (const float*)d_in[0];
  const float* Wq   = (const float*)d_in[1];
  const float* Wk   = (const float*)d_in[2];
  const float* Wv   = (const float*)d_in[3];
  const float* Wo   = (const float*)d_in[4];
  const float* fcos = (const float*)d_in[5];
  const float* fsin = (const float*)d_in[6];
  char* ws = (char*)d_ws;

  // ws layout (PO0 overlays Xb, which is dead after the QKV GEMM):
  unsigned short* Xb    = (unsigned short*)(ws);                 // 6,291,456 B
  unsigned short* PO0   = (unsigned short*)(ws);                 // reuse
  unsigned short* QKV   = (unsigned short*)(ws + 6291456);       // 10,485,760 B
  unsigned short* Vf    = (unsigned short*)(ws + 16777216);      // 2,097,152 B
  unsigned short* attnO = (unsigned short*)(ws + 18874368);      // 6,291,456 B
  unsigned short* WT    = (unsigned short*)(ws + 25165824);      //   491,520 B
  unsigned short* WoT   = (unsigned short*)(ws + 25657344);      //   294,912 B
  unsigned short* PO1   = (unsigned short*)(ws + 25952256);      // 6,291,456 B
  float2*         ML    = (float2*)       (ws + 32243712);       //   786,432 B
  // total ~33.0 MB

  prep_kernel<<<4608, 256, 0, stream>>>(X, Wq, Wk, Wv, Wo, Xb, WT, WoT);
  gemm_kernel<NQKV, true, true><<<dim3(64, 10), 256, 0, stream>>>(Xb, WT, QKV, fcos, fsin);
  vfrag_kernel<<<dim3(32, 2, 4), 256, 0, stream>>>(QKV, Vf);
  attn_kernel<<<dim3(1536, 2), 64, 0, stream>>>(QKV, Vf, PO0, PO1, ML);
  combine_kernel<<<1536, 256, 0, stream>>>(PO0, PO1, ML, attnO);
  gemm_kernel<DMODEL, false, false><<<dim3(64, 6), 256, 0, stream>>>(attnO, WoT, (void*)d_out, nullptr, nullptr);
}